// Round 1
// baseline (1895.505 us; speedup 1.0000x reference)
//
#include <hip/hip_runtime.h>

// Problem constants (B=4, T=8, N=2048, C=64)
#define BB 4
#define TT 8
#define NN 2048
#define CC 64
#define MM 512           // N / SPATIAL_STRIDE
#define KK 32
#define H3DIM 256
#define RAD2 0.25f
#define FINF 3.4e38f

#define LDS_H_STRIDE 132  // 128 + 4 pad: avoids LDS bank conflicts on row-strided float4 reads

// ---------------------------------------------------------------------------
// Kernel 1: farthest point sampling. One wave (64 lanes) per (b,t) cloud.
// Exact jnp semantics: idx[0]=0; dist=min(dist,d); argmax picks smallest index on ties.
// ---------------------------------------------------------------------------
__global__ __launch_bounds__(64) void k_fps(const float* __restrict__ xyzs,
                                            int* __restrict__ fps_idx) {
    int bt = blockIdx.x;            // b*T + t
    int lane = threadIdx.x;         // 0..63
    __shared__ float sx[NN], sy[NN], sz[NN];
    const float* src = xyzs + (size_t)bt * NN * 3;
    for (int i = lane; i < NN; i += 64) {
        sx[i] = src[i * 3 + 0];
        sy[i] = src[i * 3 + 1];
        sz[i] = src[i * 3 + 2];
    }
    __syncthreads();

    // lane owns points p = lane*32 + j (lane-major => tie-break order preserved)
    float px[32], py[32], pz[32], dist[32];
#pragma unroll
    for (int j = 0; j < 32; ++j) {
        int p = lane * 32 + j;
        px[j] = sx[p]; py[j] = sy[p]; pz[j] = sz[p];
        dist[j] = 1e10f;
    }

    int cur = 0;
    if (lane == 0) fps_idx[bt * MM + 0] = 0;
    int pbase = lane * 32;

    for (int it = 1; it < MM; ++it) {
        float cx = sx[cur], cy = sy[cur], cz = sz[cur];   // uniform -> broadcast
        float bestd = -1.0f;
        int bestp = 0;
#pragma unroll
        for (int j = 0; j < 32; ++j) {
            float dx = px[j] - cx, dy = py[j] - cy, dz = pz[j] - cz;
            float d = dx * dx + dy * dy + dz * dz;
            float nd = fminf(dist[j], d);
            dist[j] = nd;
            if (nd > bestd) { bestd = nd; bestp = pbase + j; }  // strict > keeps smallest j
        }
        // wave argmax, tie -> smaller global index
#pragma unroll
        for (int off = 32; off >= 1; off >>= 1) {
            float od = __shfl_xor(bestd, off);
            int   op = __shfl_xor(bestp, off);
            if (od > bestd || (od == bestd && op < bestp)) { bestd = od; bestp = op; }
        }
        cur = bestp;
        if (lane == 0) fps_idx[bt * MM + it] = cur;
    }
}

// ---------------------------------------------------------------------------
// Kernel 2a: P'[bt,n,c] = feat_n[bt,n,:].W1[0:64] + xyz_n[bt,n,:].W1[128:131]
// (the per-neighbor-point part of layer 1). 16 rows per block.
// ---------------------------------------------------------------------------
__global__ __launch_bounds__(256) void k_pp(const float* __restrict__ xyzs,
                                            const float* __restrict__ feats,
                                            const float* __restrict__ w1,
                                            float* __restrict__ Pp) {
    __shared__ float sw[67 * 128];
    __shared__ float sfeat[2][68];
    int tid = threadIdx.x;
    for (int i = tid; i < 67 * 128; i += 256) {
        int r = i >> 7, c = i & 127;
        int srcr = (r < 64) ? r : (128 + (r - 64));   // rows 0..63 then 128..130
        sw[i] = w1[srcr * 128 + c];
    }
    __syncthreads();

    int r2 = tid >> 7, c = tid & 127;
    int base = blockIdx.x * 16;
    for (int rr = 0; rr < 16; rr += 2) {
        int row = base + rr + r2;          // in [0, B*T*N)
        int n = row & (NN - 1);
        int bt = row >> 11;                // / 2048
        int b = bt >> 3, t = bt & 7;
        int tn = (t + 1 < TT) ? (t + 1) : (TT - 1);
        const float* fsrc = feats + (((size_t)(b * TT + tn)) * NN + n) * CC;
        const float* xsrc = xyzs + (((size_t)(b * TT + tn)) * NN + n) * 3;
        if (c < 64) sfeat[r2][c] = fsrc[c];
        else if (c < 67) sfeat[r2][c] = xsrc[c - 64];
        __syncthreads();
        float acc = 0.f;
#pragma unroll
        for (int j = 0; j < 67; ++j) acc += sfeat[r2][j] * sw[j * 128 + c];
        Pp[(size_t)row * 128 + c] = acc;
        __syncthreads();
    }
}

// ---------------------------------------------------------------------------
// Kernel 2b: Q'[row,c] = b1[c] + f1.W1[64:128] - anchor.W1[128:131]; also emits anchors.
// ---------------------------------------------------------------------------
__global__ __launch_bounds__(256) void k_qp(const float* __restrict__ xyzs,
                                            const float* __restrict__ feats,
                                            const float* __restrict__ w1,
                                            const float* __restrict__ b1,
                                            const int* __restrict__ fps_idx,
                                            float* __restrict__ Qp,
                                            float* __restrict__ out_anchor) {
    __shared__ float sw[67 * 128];
    __shared__ float sb[128];
    __shared__ float sfeat[2][68];
    int tid = threadIdx.x;
    for (int i = tid; i < 67 * 128; i += 256) {
        int r = i >> 7, c = i & 127;
        sw[i] = w1[(64 + r) * 128 + c];    // rows 64..130
    }
    if (tid < 128) sb[tid] = b1[tid];
    __syncthreads();

    int r2 = tid >> 7, c = tid & 127;
    int base = blockIdx.x * 16;
    for (int rr = 0; rr < 16; rr += 2) {
        int row = base + rr + r2;          // in [0, B*T*M)
        int bt = row >> 9;                 // / 512
        int aidx = fps_idx[row];
        const float* fsrc = feats + ((size_t)bt * NN + aidx) * CC;   // frame t itself
        const float* xsrc = xyzs + ((size_t)bt * NN + aidx) * 3;
        if (c < 64) sfeat[r2][c] = fsrc[c];
        else if (c < 67) sfeat[r2][c] = xsrc[c - 64];
        __syncthreads();
        float acc = sb[c];
#pragma unroll
        for (int j = 0; j < 64; ++j) acc += sfeat[r2][j] * sw[j * 128 + c];
#pragma unroll
        for (int j = 0; j < 3; ++j) acc -= sfeat[r2][64 + j] * sw[(64 + j) * 128 + c];
        Qp[(size_t)row * 128 + c] = acc;
        if (c < 3) out_anchor[(size_t)row * 3 + c] = sfeat[r2][64 + c];
        __syncthreads();
    }
}

// ---------------------------------------------------------------------------
// Kernel 3: exact stable top-K=32 nearest (ascending d, ties -> smaller index)
// + radius filter. One wave per anchor (4 serial anchors/wave, 4 waves/block).
// ---------------------------------------------------------------------------
__global__ __launch_bounds__(256) void k_knn(const float* __restrict__ xyzs,
                                             const float* __restrict__ anchors,
                                             int* __restrict__ idxk) {
    __shared__ float sx[NN], sy[NN], sz[NN];
    int tid = threadIdx.x;
    int wave = tid >> 6, lane = tid & 63;
    int bt = blockIdx.x >> 5;              // 32 blocks per (b,t)
    int sub = blockIdx.x & 31;
    int b = bt >> 3, t = bt & 7;
    int tn = (t + 1 < TT) ? (t + 1) : (TT - 1);
    const float* src = xyzs + ((size_t)(b * TT + tn)) * NN * 3;
    for (int i = tid; i < NN; i += 256) {
        sx[i] = src[i * 3 + 0];
        sy[i] = src[i * 3 + 1];
        sz[i] = src[i * 3 + 2];
    }
    __syncthreads();

    for (int a = 0; a < 4; ++a) {
        int mrow = bt * MM + sub * 16 + wave * 4 + a;
        float ax = anchors[mrow * 3 + 0];
        float ay = anchors[mrow * 3 + 1];
        float az = anchors[mrow * 3 + 2];
        float d[32];
#pragma unroll
        for (int j = 0; j < 32; ++j) {
            int p = j * 64 + lane;
            float dx = sx[p] - ax, dy = sy[p] - ay, dz = sz[p] - az;
            d[j] = dx * dx + dy * dy + dz * dz;
        }
        int pstar = -1;
        int p0 = 0;
        for (int r = 0; r < KK; ++r) {
            float bestd = FINF;
            int bestp = 0x7fffffff;
#pragma unroll
            for (int j = 0; j < 32; ++j) {
                int pj = j * 64 + lane;
                float dj = (pj == pstar) ? FINF : d[j];  // invalidate last winner
                d[j] = dj;
                if (dj < bestd) { bestd = dj; bestp = pj; }  // strict < keeps smallest p
            }
#pragma unroll
            for (int off = 32; off >= 1; off >>= 1) {
                float od = __shfl_xor(bestd, off);
                int   op = __shfl_xor(bestp, off);
                if (od < bestd || (od == bestd && op < bestp)) { bestd = od; bestp = op; }
            }
            if (r == 0) p0 = bestp;
            int outp = (bestd <= RAD2) ? bestp : p0;     // radius replacement
            if (lane == 0) idxk[(size_t)mrow * KK + r] = outp;
            pstar = bestp;
        }
    }
}

// ---------------------------------------------------------------------------
// Kernel 4: fused h1-gather + GEMM(w2) + GEMM(w3) + max over K.
// 2 anchors (64 rows) per block. Dynamic LDS: h1[64][132] | wbuf[128][128] | h2[64][132]
// max_k relu(x+b) == relu(max_k x + b)  (monotone), so max is fused on raw dots.
// ---------------------------------------------------------------------------
__global__ __launch_bounds__(256, 1) void k_mlp(const float* __restrict__ Pp,
                                                const float* __restrict__ Qp,
                                                const int* __restrict__ idxk,
                                                const float* __restrict__ w2,
                                                const float* __restrict__ b2,
                                                const float* __restrict__ w3,
                                                const float* __restrict__ b3,
                                                float* __restrict__ out_feat) {
    extern __shared__ float smem[];
    float* h1 = smem;                        // 64*132
    float* wb = smem + 64 * LDS_H_STRIDE;    // 128*128
    float* h2 = wb + 128 * 128;              // 64*132
    int tid = threadIdx.x;
    int arow0 = blockIdx.x * 2;              // first of 2 anchor rows
    int bt = arow0 >> 9;                     // / 512

    // stage w2
    for (int i = tid * 4; i < 128 * 128; i += 256 * 4) {
        *(float4*)(wb + i) = *(const float4*)(w2 + i);
    }
    // build h1 = relu(P'[nk] + Q'[m])
    {
        int r = tid >> 2;                    // 0..63
        int cq = tid & 3;
        int ml = r >> 5;                     // anchor within block
        int k = r & 31;
        int arow = arow0 + ml;
        int nk = idxk[(size_t)arow * KK + k];
        const float* psrc = Pp + ((size_t)bt * NN + nk) * 128 + cq * 32;
        const float* qsrc = Qp + (size_t)arow * 128 + cq * 32;
        float* dst = h1 + r * LDS_H_STRIDE + cq * 32;
#pragma unroll
        for (int i = 0; i < 32; i += 4) {
            float4 p4 = *(const float4*)(psrc + i);
            float4 q4 = *(const float4*)(qsrc + i);
            float4 o;
            o.x = fmaxf(p4.x + q4.x, 0.f);
            o.y = fmaxf(p4.y + q4.y, 0.f);
            o.z = fmaxf(p4.z + q4.z, 0.f);
            o.w = fmaxf(p4.w + q4.w, 0.f);
            *(float4*)(dst + i) = o;
        }
    }
    __syncthreads();

    int rg = tid >> 5, cg = tid & 31;        // 8 row-groups x 32 col-groups

    // ---- phase B: h2 = relu(h1 @ w2 + b2), 8x4 tile per thread ----
    {
        float acc[8][4];
#pragma unroll
        for (int i = 0; i < 8; ++i)
#pragma unroll
            for (int j = 0; j < 4; ++j) acc[i][j] = 0.f;
#pragma unroll 2
        for (int k = 0; k < 128; k += 4) {
            float4 a4[8];
#pragma unroll
            for (int i = 0; i < 8; ++i)
                a4[i] = *(const float4*)(h1 + (rg * 8 + i) * LDS_H_STRIDE + k);
#pragma unroll
            for (int kk = 0; kk < 4; ++kk) {
                float4 b4 = *(const float4*)(wb + (k + kk) * 128 + cg * 4);
#pragma unroll
                for (int i = 0; i < 8; ++i) {
                    float av = (kk == 0) ? a4[i].x : (kk == 1) ? a4[i].y : (kk == 2) ? a4[i].z : a4[i].w;
                    acc[i][0] += av * b4.x;
                    acc[i][1] += av * b4.y;
                    acc[i][2] += av * b4.z;
                    acc[i][3] += av * b4.w;
                }
            }
        }
        float4 bb = *(const float4*)(b2 + cg * 4);
#pragma unroll
        for (int i = 0; i < 8; ++i) {
            float4 o;
            o.x = fmaxf(acc[i][0] + bb.x, 0.f);
            o.y = fmaxf(acc[i][1] + bb.y, 0.f);
            o.z = fmaxf(acc[i][2] + bb.z, 0.f);
            o.w = fmaxf(acc[i][3] + bb.w, 0.f);
            *(float4*)(h2 + (rg * 8 + i) * LDS_H_STRIDE + cg * 4) = o;
        }
    }

    // ---- phase C: out = relu(max_k (h2 @ w3) + b3), in two 128-col halves ----
    for (int half = 0; half < 2; ++half) {
        __syncthreads();                      // prior wb readers done
        for (int i = tid * 4; i < 128 * 128; i += 256 * 4) {
            int r = i >> 7, c = i & 127;
            *(float4*)(wb + i) = *(const float4*)(w3 + r * H3DIM + half * 128 + c);
        }
        __syncthreads();                      // wb ready

        float acc[8][4];
#pragma unroll
        for (int i = 0; i < 8; ++i)
#pragma unroll
            for (int j = 0; j < 4; ++j) acc[i][j] = 0.f;
#pragma unroll 2
        for (int k = 0; k < 128; k += 4) {
            float4 a4[8];
#pragma unroll
            for (int i = 0; i < 8; ++i)
                a4[i] = *(const float4*)(h2 + (rg * 8 + i) * LDS_H_STRIDE + k);
#pragma unroll
            for (int kk = 0; kk < 4; ++kk) {
                float4 b4 = *(const float4*)(wb + (k + kk) * 128 + cg * 4);
#pragma unroll
                for (int i = 0; i < 8; ++i) {
                    float av = (kk == 0) ? a4[i].x : (kk == 1) ? a4[i].y : (kk == 2) ? a4[i].z : a4[i].w;
                    acc[i][0] += av * b4.x;
                    acc[i][1] += av * b4.y;
                    acc[i][2] += av * b4.z;
                    acc[i][3] += av * b4.w;
                }
            }
        }
        // local max over this thread's 8 K-rows (all within one anchor: rg 0..3 -> anchor0)
        float4 cm;
        cm.x = acc[0][0]; cm.y = acc[0][1]; cm.z = acc[0][2]; cm.w = acc[0][3];
#pragma unroll
        for (int i = 1; i < 8; ++i) {
            cm.x = fmaxf(cm.x, acc[i][0]);
            cm.y = fmaxf(cm.y, acc[i][1]);
            cm.z = fmaxf(cm.z, acc[i][2]);
            cm.w = fmaxf(cm.w, acc[i][3]);
        }
        float* red = h1;                      // reuse as [8][128]
        *(float4*)(red + rg * 128 + cg * 4) = cm;
        __syncthreads();

        int a = tid >> 7, c = tid & 127;      // a: anchor-in-block, c: col in half
        float v = fmaxf(fmaxf(red[(a * 4 + 0) * 128 + c], red[(a * 4 + 1) * 128 + c]),
                        fmaxf(red[(a * 4 + 2) * 128 + c], red[(a * 4 + 3) * 128 + c]));
        v = fmaxf(v + b3[half * 128 + c], 0.f);
        out_feat[(size_t)(arow0 + a) * H3DIM + half * 128 + c] = v;
    }
}

// ---------------------------------------------------------------------------
extern "C" void kernel_launch(void* const* d_in, const int* in_sizes, int n_in,
                              void* d_out, int out_size, void* d_ws, size_t ws_size,
                              hipStream_t stream) {
    const float* xyzs  = (const float*)d_in[0];
    const float* feats = (const float*)d_in[1];
    const float* w1 = (const float*)d_in[2];
    const float* b1 = (const float*)d_in[3];
    const float* w2 = (const float*)d_in[4];
    const float* b2 = (const float*)d_in[5];
    const float* w3 = (const float*)d_in[6];
    const float* b3 = (const float*)d_in[7];

    float* out_anchor = (float*)d_out;
    float* out_feat = out_anchor + (size_t)BB * TT * MM * 3;

    // workspace layout
    char* ws = (char*)d_ws;
    int* fps_idx = (int*)ws;                               // B*T*M ints        = 64 KB
    int* idxk = (int*)(ws + 65536);                        // B*T*M*K ints      = 2 MB
    float* Pp = (float*)(ws + 65536 + 2097152);            // B*T*N*128 floats  = 32 MB
    float* Qp = Pp + (size_t)BB * TT * NN * 128;           // B*T*M*128 floats  = 8 MB
    if (ws_size < (size_t)(65536 + 2097152) + ((size_t)BB * TT * NN * 128 + (size_t)BB * TT * MM * 128) * 4)
        return;

    k_fps<<<BB * TT, 64, 0, stream>>>(xyzs, fps_idx);
    k_pp<<<BB * TT * NN / 16, 256, 0, stream>>>(xyzs, feats, w1, Pp);
    k_qp<<<BB * TT * MM / 16, 256, 0, stream>>>(xyzs, feats, w1, b1, fps_idx, Qp, out_anchor);
    k_knn<<<BB * TT * 32, 256, 0, stream>>>(xyzs, out_anchor, idxk);

    const int k4_lds = (64 * LDS_H_STRIDE + 128 * 128 + 64 * LDS_H_STRIDE) * 4;  // 133120 B
    hipFuncSetAttribute((const void*)k_mlp, hipFuncAttributeMaxDynamicSharedMemorySize, k4_lds);
    k_mlp<<<BB * TT * MM / 2, 256, k4_lds, stream>>>(Pp, Qp, idxk, w2, b2, w3, b3, out_feat);
}

// Round 2
// 1074.674 us; speedup vs baseline: 1.7638x; 1.7638x over previous
//
#include <hip/hip_runtime.h>

// Problem constants (B=4, T=8, N=2048, C=64)
#define BB 4
#define TT 8
#define NN 2048
#define CC 64
#define MM 512           // N / SPATIAL_STRIDE
#define KK 32
#define H3DIM 256
#define RAD2 0.25f
#define FINF 3.4e38f

typedef _Float16 f16x8 __attribute__((ext_vector_type(8)));
typedef float f32x4 __attribute__((ext_vector_type(4)));

// ---------------------------------------------------------------------------
// Kernel 1: farthest point sampling. One wave (64 lanes) per (b,t) cloud.
// ---------------------------------------------------------------------------
__global__ __launch_bounds__(64) void k_fps(const float* __restrict__ xyzs,
                                            int* __restrict__ fps_idx) {
    int bt = blockIdx.x;
    int lane = threadIdx.x;
    __shared__ float sx[NN], sy[NN], sz[NN];
    const float* src = xyzs + (size_t)bt * NN * 3;
    for (int i = lane; i < NN; i += 64) {
        sx[i] = src[i * 3 + 0];
        sy[i] = src[i * 3 + 1];
        sz[i] = src[i * 3 + 2];
    }
    __syncthreads();

    float px[32], py[32], pz[32], dist[32];
#pragma unroll
    for (int j = 0; j < 32; ++j) {
        int p = lane * 32 + j;
        px[j] = sx[p]; py[j] = sy[p]; pz[j] = sz[p];
        dist[j] = 1e10f;
    }

    int cur = 0;
    if (lane == 0) fps_idx[bt * MM + 0] = 0;
    int pbase = lane * 32;

    for (int it = 1; it < MM; ++it) {
        float cx = sx[cur], cy = sy[cur], cz = sz[cur];
        float bestd = -1.0f;
        int bestp = 0;
#pragma unroll
        for (int j = 0; j < 32; ++j) {
            float dx = px[j] - cx, dy = py[j] - cy, dz = pz[j] - cz;
            float d = dx * dx + dy * dy + dz * dz;
            float nd = fminf(dist[j], d);
            dist[j] = nd;
            if (nd > bestd) { bestd = nd; bestp = pbase + j; }
        }
#pragma unroll
        for (int off = 32; off >= 1; off >>= 1) {
            float od = __shfl_xor(bestd, off);
            int   op = __shfl_xor(bestp, off);
            if (od > bestd || (od == bestd && op < bestp)) { bestd = od; bestp = op; }
        }
        cur = bestp;
        if (lane == 0) fps_idx[bt * MM + it] = cur;
    }
}

// ---------------------------------------------------------------------------
// Kernel 2a: P'[bt,n,c] (fp16 out) = feat_n.W1[0:64] + xyz_n.W1[128:131]
// ---------------------------------------------------------------------------
__global__ __launch_bounds__(256) void k_pp(const float* __restrict__ xyzs,
                                            const float* __restrict__ feats,
                                            const float* __restrict__ w1,
                                            _Float16* __restrict__ Pp) {
    __shared__ float sw[67 * 128];
    __shared__ float sfeat[2][68];
    int tid = threadIdx.x;
    for (int i = tid; i < 67 * 128; i += 256) {
        int r = i >> 7, c = i & 127;
        int srcr = (r < 64) ? r : (128 + (r - 64));
        sw[i] = w1[srcr * 128 + c];
    }
    __syncthreads();

    int r2 = tid >> 7, c = tid & 127;
    int base = blockIdx.x * 16;
    for (int rr = 0; rr < 16; rr += 2) {
        int row = base + rr + r2;
        int n = row & (NN - 1);
        int bt = row >> 11;
        int b = bt >> 3, t = bt & 7;
        int tn = (t + 1 < TT) ? (t + 1) : (TT - 1);
        const float* fsrc = feats + (((size_t)(b * TT + tn)) * NN + n) * CC;
        const float* xsrc = xyzs + (((size_t)(b * TT + tn)) * NN + n) * 3;
        if (c < 64) sfeat[r2][c] = fsrc[c];
        else if (c < 67) sfeat[r2][c] = xsrc[c - 64];
        __syncthreads();
        float acc = 0.f;
#pragma unroll
        for (int j = 0; j < 67; ++j) acc += sfeat[r2][j] * sw[j * 128 + c];
        Pp[(size_t)row * 128 + c] = (_Float16)acc;
        __syncthreads();
    }
}

// ---------------------------------------------------------------------------
// Kernel 2b: Q'[row,c] = b1[c] + f1.W1[64:128] - anchor.W1[128:131]; + anchors out.
// ---------------------------------------------------------------------------
__global__ __launch_bounds__(256) void k_qp(const float* __restrict__ xyzs,
                                            const float* __restrict__ feats,
                                            const float* __restrict__ w1,
                                            const float* __restrict__ b1,
                                            const int* __restrict__ fps_idx,
                                            float* __restrict__ Qp,
                                            float* __restrict__ out_anchor) {
    __shared__ float sw[67 * 128];
    __shared__ float sb[128];
    __shared__ float sfeat[2][68];
    int tid = threadIdx.x;
    for (int i = tid; i < 67 * 128; i += 256) {
        int r = i >> 7, c = i & 127;
        sw[i] = w1[(64 + r) * 128 + c];
    }
    if (tid < 128) sb[tid] = b1[tid];
    __syncthreads();

    int r2 = tid >> 7, c = tid & 127;
    int base = blockIdx.x * 16;
    for (int rr = 0; rr < 16; rr += 2) {
        int row = base + rr + r2;
        int bt = row >> 9;
        int aidx = fps_idx[row];
        const float* fsrc = feats + ((size_t)bt * NN + aidx) * CC;
        const float* xsrc = xyzs + ((size_t)bt * NN + aidx) * 3;
        if (c < 64) sfeat[r2][c] = fsrc[c];
        else if (c < 67) sfeat[r2][c] = xsrc[c - 64];
        __syncthreads();
        float acc = sb[c];
#pragma unroll
        for (int j = 0; j < 64; ++j) acc += sfeat[r2][j] * sw[j * 128 + c];
#pragma unroll
        for (int j = 0; j < 3; ++j) acc -= sfeat[r2][64 + j] * sw[(64 + j) * 128 + c];
        Qp[(size_t)row * 128 + c] = acc;
        if (c < 3) out_anchor[(size_t)row * 3 + c] = sfeat[r2][64 + c];
        __syncthreads();
    }
}

// ---------------------------------------------------------------------------
// Kernel 3: exact stable top-K=32 nearest + radius filter. One wave per anchor.
// ---------------------------------------------------------------------------
__global__ __launch_bounds__(256) void k_knn(const float* __restrict__ xyzs,
                                             const float* __restrict__ anchors,
                                             int* __restrict__ idxk) {
    __shared__ float sx[NN], sy[NN], sz[NN];
    int tid = threadIdx.x;
    int wave = tid >> 6, lane = tid & 63;
    int bt = blockIdx.x >> 5;
    int sub = blockIdx.x & 31;
    int b = bt >> 3, t = bt & 7;
    int tn = (t + 1 < TT) ? (t + 1) : (TT - 1);
    const float* src = xyzs + ((size_t)(b * TT + tn)) * NN * 3;
    for (int i = tid; i < NN; i += 256) {
        sx[i] = src[i * 3 + 0];
        sy[i] = src[i * 3 + 1];
        sz[i] = src[i * 3 + 2];
    }
    __syncthreads();

    for (int a = 0; a < 4; ++a) {
        int mrow = bt * MM + sub * 16 + wave * 4 + a;
        float ax = anchors[mrow * 3 + 0];
        float ay = anchors[mrow * 3 + 1];
        float az = anchors[mrow * 3 + 2];
        float d[32];
#pragma unroll
        for (int j = 0; j < 32; ++j) {
            int p = j * 64 + lane;
            float dx = sx[p] - ax, dy = sy[p] - ay, dz = sz[p] - az;
            d[j] = dx * dx + dy * dy + dz * dz;
        }
        int pstar = -1;
        int p0 = 0;
        for (int r = 0; r < KK; ++r) {
            float bestd = FINF;
            int bestp = 0x7fffffff;
#pragma unroll
            for (int j = 0; j < 32; ++j) {
                int pj = j * 64 + lane;
                float dj = (pj == pstar) ? FINF : d[j];
                d[j] = dj;
                if (dj < bestd) { bestd = dj; bestp = pj; }
            }
#pragma unroll
            for (int off = 32; off >= 1; off >>= 1) {
                float od = __shfl_xor(bestd, off);
                int   op = __shfl_xor(bestp, off);
                if (od < bestd || (od == bestd && op < bestp)) { bestd = od; bestp = op; }
            }
            if (r == 0) p0 = bestp;
            int outp = (bestd <= RAD2) ? bestp : p0;
            if (lane == 0) idxk[(size_t)mrow * KK + r] = outp;
            pstar = bestp;
        }
    }
}

// ---------------------------------------------------------------------------
// Kernel 4: persistent-block fp16 MFMA MLP (layers 2+3) + max over K.
// 256 blocks (1/CU). LDS: w2^T fp16 (32K) | w3^T fp16 (64K) | h1 (16K) | h2 (16K)
// staged ONCE per block; 32 chunks x 2 anchors streamed through h1/h2.
// XOR swizzle: byte ^= (row&7)<<4 on all 4 tiles (write and read sides).
// MFMA 16x16x32_f16: A row=l&15 k=(l>>4)*8+i ; B col=l&15 ; D col=l&15 row=(l>>4)*4+r.
// ---------------------------------------------------------------------------
#define SM_W2 0
#define SM_W3 32768
#define SM_H1 98304
#define SM_H2 114688
#define SM_B2 131072
#define SM_B3 131584
#define SM_TOTAL 132608

__global__ __launch_bounds__(256, 1) void k_mlp(const _Float16* __restrict__ Pp,
                                                const float* __restrict__ Qp,
                                                const int* __restrict__ idxk,
                                                const float* __restrict__ w2,
                                                const float* __restrict__ b2,
                                                const float* __restrict__ w3,
                                                const float* __restrict__ b3,
                                                float* __restrict__ out_feat) {
    extern __shared__ char smem[];
    int tid = threadIdx.x;
    int bid = blockIdx.x;                  // 0..255

    // ---- one-time weight staging (transposed to [n][k] fp16, swizzled) ----
    for (int i = tid; i < 128 * 128; i += 256) {
        int n = i & 127, kk = i >> 7;
        _Float16 v = (_Float16)w2[kk * 128 + n];
        *(_Float16*)(smem + SM_W2 + n * 256 + ((2 * kk) ^ ((n & 7) << 4))) = v;
    }
    for (int i = tid; i < 256 * 128; i += 256) {
        int n = i & 255, kk = i >> 8;
        _Float16 v = (_Float16)w3[kk * 256 + n];
        *(_Float16*)(smem + SM_W3 + n * 256 + ((2 * kk) ^ ((n & 7) << 4))) = v;
    }
    if (tid < 128) *(float*)(smem + SM_B2 + tid * 4) = b2[tid];
    *(float*)(smem + SM_B3 + tid * 4) = b3[tid];   // tid<256 always
    __syncthreads();

    int lane = tid & 63;
    int w = tid >> 6;
    int wm = w >> 1, wn = w & 1;           // wave grid: 2 anchors x 2 col-halves
    int l15 = lane & 15, g = lane >> 4;
    int hswz = (l15 & 7) << 4;             // swizzle for A-frag rows (row&7 == l15&7)

    const f32x4 zero4 = {0.f, 0.f, 0.f, 0.f};

    for (int c = 0; c < 32; ++c) {
        int a0 = bid * 64 + c * 2;         // global anchor row (anchor 0 of pair)
        int bt = a0 >> 9;

        // ---- build h1 = relu(P'[nk] + Q'[a]) -> fp16, swizzled [64][128] ----
        {
            int r = tid >> 2, seg = tid & 3;
            int arow = a0 + (r >> 5);
            int kidx = r & 31;
            int nk = idxk[(size_t)arow * KK + kidx];
            const _Float16* ps = Pp + ((size_t)(bt * NN + nk)) * 128 + seg * 32;
            const float* qs = Qp + (size_t)arow * 128 + seg * 32;
            int rowbase = SM_H1 + r * 256;
            int swz = (r & 7) << 4;
#pragma unroll
            for (int i = 0; i < 4; ++i) {
                f16x8 pv = *(const f16x8*)(ps + i * 8);
                f32x4 q0 = *(const f32x4*)(qs + i * 8);
                f32x4 q1 = *(const f32x4*)(qs + i * 8 + 4);
                f16x8 hv;
#pragma unroll
                for (int j = 0; j < 4; ++j) hv[j] = (_Float16)fmaxf((float)pv[j] + q0[j], 0.f);
#pragma unroll
                for (int j = 0; j < 4; ++j) hv[4 + j] = (_Float16)fmaxf((float)pv[4 + j] + q1[j], 0.f);
                *(f16x8*)(smem + rowbase + ((seg * 64 + i * 16) ^ swz)) = hv;
            }
        }
        __syncthreads();

        // ---- layer 2: h2 = relu(h1 @ w2 + b2) ----
        f32x4 acc2[2][4];
#pragma unroll
        for (int m = 0; m < 2; ++m)
#pragma unroll
            for (int n = 0; n < 4; ++n) acc2[m][n] = zero4;

#pragma unroll
        for (int ks = 0; ks < 4; ++ks) {
            int kbyte = ks * 64 + g * 16;
            f16x8 af[2], bf[4];
#pragma unroll
            for (int m = 0; m < 2; ++m) {
                int row = wm * 32 + m * 16 + l15;
                af[m] = *(const f16x8*)(smem + SM_H1 + row * 256 + (kbyte ^ hswz));
            }
#pragma unroll
            for (int n = 0; n < 4; ++n) {
                int col = wn * 64 + n * 16 + l15;
                bf[n] = *(const f16x8*)(smem + SM_W2 + col * 256 + (kbyte ^ hswz));
            }
#pragma unroll
            for (int m = 0; m < 2; ++m)
#pragma unroll
                for (int n = 0; n < 4; ++n)
                    acc2[m][n] = __builtin_amdgcn_mfma_f32_16x16x32_f16(af[m], bf[n], acc2[m][n], 0, 0, 0);
        }
        // epilogue: +b2, relu, fp16 -> h2 (swizzled scatter, 2B stores)
#pragma unroll
        for (int m = 0; m < 2; ++m)
#pragma unroll
            for (int n = 0; n < 4; ++n) {
                int col = wn * 64 + n * 16 + l15;
                float bb = *(const float*)(smem + SM_B2 + col * 4);
#pragma unroll
                for (int r = 0; r < 4; ++r) {
                    int row = wm * 32 + m * 16 + g * 4 + r;
                    float v = fmaxf(acc2[m][n][r] + bb, 0.f);
                    *(_Float16*)(smem + SM_H2 + row * 256 + ((2 * col) ^ ((row & 7) << 4))) = (_Float16)v;
                }
            }
        __syncthreads();

        // ---- layer 3: max_k(h2 @ w3), +b3, relu, store ----
        f32x4 acc3[2][8];
#pragma unroll
        for (int m = 0; m < 2; ++m)
#pragma unroll
            for (int n = 0; n < 8; ++n) acc3[m][n] = zero4;

#pragma unroll
        for (int ks = 0; ks < 4; ++ks) {
            int kbyte = ks * 64 + g * 16;
            f16x8 af[2], bf[8];
#pragma unroll
            for (int m = 0; m < 2; ++m) {
                int row = wm * 32 + m * 16 + l15;
                af[m] = *(const f16x8*)(smem + SM_H2 + row * 256 + (kbyte ^ hswz));
            }
#pragma unroll
            for (int n = 0; n < 8; ++n) {
                int col = wn * 128 + n * 16 + l15;
                bf[n] = *(const f16x8*)(smem + SM_W3 + col * 256 + (kbyte ^ hswz));
            }
#pragma unroll
            for (int m = 0; m < 2; ++m)
#pragma unroll
                for (int n = 0; n < 8; ++n)
                    acc3[m][n] = __builtin_amdgcn_mfma_f32_16x16x32_f16(af[m], bf[n], acc3[m][n], 0, 0, 0);
        }
#pragma unroll
        for (int n = 0; n < 8; ++n) {
            int col = wn * 128 + n * 16 + l15;
            float s = acc3[0][n][0];
#pragma unroll
            for (int r = 1; r < 4; ++r) s = fmaxf(s, acc3[0][n][r]);
#pragma unroll
            for (int r = 0; r < 4; ++r) s = fmaxf(s, acc3[1][n][r]);
            s = fmaxf(s, __shfl_xor(s, 16));
            s = fmaxf(s, __shfl_xor(s, 32));
            if (g == 0) {
                float bb = *(const float*)(smem + SM_B3 + col * 4);
                out_feat[(size_t)(a0 + wm) * H3DIM + col] = fmaxf(s + bb, 0.f);
            }
        }
        __syncthreads();   // h2 (and h1) free for next chunk
    }
}

// ---------------------------------------------------------------------------
extern "C" void kernel_launch(void* const* d_in, const int* in_sizes, int n_in,
                              void* d_out, int out_size, void* d_ws, size_t ws_size,
                              hipStream_t stream) {
    const float* xyzs  = (const float*)d_in[0];
    const float* feats = (const float*)d_in[1];
    const float* w1 = (const float*)d_in[2];
    const float* b1 = (const float*)d_in[3];
    const float* w2 = (const float*)d_in[4];
    const float* b2 = (const float*)d_in[5];
    const float* w3 = (const float*)d_in[6];
    const float* b3 = (const float*)d_in[7];

    float* out_anchor = (float*)d_out;
    float* out_feat = out_anchor + (size_t)BB * TT * MM * 3;

    // workspace layout
    char* ws = (char*)d_ws;
    int* fps_idx = (int*)ws;                                   // 64 KB
    int* idxk = (int*)(ws + 65536);                            // 2 MB
    _Float16* Pp = (_Float16*)(ws + 65536 + 2097152);          // B*T*N*128 fp16 = 16 MB
    float* Qp = (float*)(ws + 65536 + 2097152 + 16777216);     // B*T*M*128 fp32 = 8 MB
    if (ws_size < (size_t)(65536 + 2097152 + 16777216) + (size_t)BB * TT * MM * 128 * 4)
        return;

    k_fps<<<BB * TT, 64, 0, stream>>>(xyzs, fps_idx);
    k_pp<<<BB * TT * NN / 16, 256, 0, stream>>>(xyzs, feats, w1, Pp);
    k_qp<<<BB * TT * MM / 16, 256, 0, stream>>>(xyzs, feats, w1, b1, fps_idx, Qp, out_anchor);
    k_knn<<<BB * TT * 32, 256, 0, stream>>>(xyzs, out_anchor, idxk);

    hipFuncSetAttribute((const void*)k_mlp, hipFuncAttributeMaxDynamicSharedMemorySize, SM_TOTAL);
    k_mlp<<<256, 256, SM_TOTAL, stream>>>(Pp, Qp, idxk, w2, b2, w3, b3, out_feat);
}

// Round 4
// 718.569 us; speedup vs baseline: 2.6379x; 1.4956x over previous
//
#include <hip/hip_runtime.h>

// Problem constants (B=4, T=8, N=2048, C=64)
#define BB 4
#define TT 8
#define NN 2048
#define CC 64
#define MM 512           // N / SPATIAL_STRIDE
#define KK 32
#define H3DIM 256
#define RAD2 0.25f
#define FINF 3.4e38f

typedef _Float16 f16x8 __attribute__((ext_vector_type(8)));
typedef _Float16 f16x4 __attribute__((ext_vector_type(4)));
typedef float f32x4 __attribute__((ext_vector_type(4)));

// ---------------------------------------------------------------------------
// DPP wave-64 max reduce: ~2 VALU per level, result broadcast from lane 63.
// ctrl must be a compile-time constant -> template parameter.
// ---------------------------------------------------------------------------
template <int CTRL>
__device__ __forceinline__ float dpp_max_step(float x) {
    int xi = __builtin_bit_cast(int, x);
    int yi = __builtin_amdgcn_update_dpp(xi, xi, CTRL, 0xf, 0xf, false);
    return fmaxf(x, __builtin_bit_cast(float, yi));
}
__device__ __forceinline__ float wave_max64(float x) {
    x = dpp_max_step<0x111>(x);   // row_shr:1
    x = dpp_max_step<0x112>(x);   // row_shr:2
    x = dpp_max_step<0x114>(x);   // row_shr:4
    x = dpp_max_step<0x118>(x);   // row_shr:8
    x = dpp_max_step<0x142>(x);   // row_bcast:15
    x = dpp_max_step<0x143>(x);   // row_bcast:31
    return __builtin_bit_cast(float, __builtin_amdgcn_readlane(__builtin_bit_cast(int, x), 63));
}

// ---------------------------------------------------------------------------
// Kernel 1: farthest point sampling. 4 waves (256 thr) per (b,t) cloud.
// Points tid-major: p = tid*8 + j, so index order is preserved for tie-breaks.
// ---------------------------------------------------------------------------
__global__ __launch_bounds__(256) void k_fps(const float* __restrict__ xyzs,
                                             int* __restrict__ fps_idx) {
    int bt = blockIdx.x;
    int tid = threadIdx.x;
    int lane = tid & 63, w = tid >> 6;
    __shared__ float sx[NN], sy[NN], sz[NN];
    __shared__ float pd[2][4];
    __shared__ int   pi[2][4];
    const float* src = xyzs + (size_t)bt * NN * 3;
    for (int i = tid; i < NN; i += 256) {
        sx[i] = src[i * 3 + 0];
        sy[i] = src[i * 3 + 1];
        sz[i] = src[i * 3 + 2];
    }
    __syncthreads();

    float px[8], py[8], pz[8], dist[8];
#pragma unroll
    for (int j = 0; j < 8; ++j) {
        int p = tid * 8 + j;
        px[j] = sx[p]; py[j] = sy[p]; pz[j] = sz[p];
        dist[j] = 1e10f;
    }

    int cur = 0;
    if (tid == 0) fps_idx[bt * MM + 0] = 0;
    int pbase = tid * 8;

    for (int it = 1; it < MM; ++it) {
        float cx = sx[cur], cy = sy[cur], cz = sz[cur];   // broadcast reads
        float bestd = -1.0f;
        int bestp = 0;
#pragma unroll
        for (int j = 0; j < 8; ++j) {
            float dx = px[j] - cx, dy = py[j] - cy, dz = pz[j] - cz;
            float d = dx * dx + dy * dy + dz * dz;
            float nd = fminf(dist[j], d);
            dist[j] = nd;
            if (nd > bestd) { bestd = nd; bestp = pbase + j; }  // strict > keeps smallest j
        }
        // wave argmax: value via DPP tree, index via ballot (lowest lane = smallest index)
        float wmax = wave_max64(bestd);
        unsigned long long mask = __ballot(bestd == wmax);
        int wl = __ffsll(mask) - 1;
        int wbp = __builtin_amdgcn_readlane(bestp, wl);
        if (lane == 0) { pd[it & 1][w] = wmax; pi[it & 1][w] = wbp; }
        __syncthreads();
        float bd = pd[it & 1][0];
        int bp = pi[it & 1][0];
#pragma unroll
        for (int q = 1; q < 4; ++q) {
            float d2 = pd[it & 1][q];
            int p2 = pi[it & 1][q];
            if (d2 > bd) { bd = d2; bp = p2; }   // strict > : earlier wave wins ties
        }
        cur = bp;
        if (tid == 0) fps_idx[bt * MM + it] = cur;
    }
}

// ---------------------------------------------------------------------------
// Kernel 2a: P'[row,c] (fp16) = feat_n.W1[0:64] + xyz_n.W1[128:131]
// 64 rows/block, register-tiled 8 rows x 4 cols per thread, k padded to 68.
// ---------------------------------------------------------------------------
__global__ __launch_bounds__(256) void k_pp(const float* __restrict__ xyzs,
                                            const float* __restrict__ feats,
                                            const float* __restrict__ w1,
                                            _Float16* __restrict__ Pp) {
    __shared__ float sw[68 * 128];
    __shared__ float sin_[64 * 68];
    int tid = threadIdx.x;
    for (int i = tid; i < 68 * 128; i += 256) {
        int r = i >> 7, c = i & 127;
        float v = 0.f;
        if (r < 64) v = w1[r * 128 + c];
        else if (r < 67) v = w1[(128 + r - 64) * 128 + c];
        sw[i] = v;
    }
    int row0 = blockIdx.x * 64;
    int bt = row0 >> 11;
    int b = bt >> 3, t = bt & 7;
    int tn = (t + 1 < TT) ? (t + 1) : (TT - 1);
    size_t nbase = (size_t)(b * TT + tn) * NN + (row0 & (NN - 1));
    const float* fsrc = feats + nbase * CC;
    const float* xsrc = xyzs + nbase * 3;
    for (int i = tid; i < 1024; i += 256) {           // 64 rows x 64 feats
        float4 v = ((const float4*)fsrc)[i];
        int r = i >> 4, c = (i & 15) * 4;
        *(float4*)&sin_[r * 68 + c] = v;
    }
    if (tid < 192) {                                   // 64 rows x 3 xyz
        int r = tid / 3, c = tid - r * 3;
        sin_[r * 68 + 64 + c] = xsrc[tid];
    }
    if (tid < 64) sin_[tid * 68 + 67] = 0.f;           // zero pad k=67
    __syncthreads();

    int rowg = tid >> 5, colg = tid & 31;
    float4 acc[8];
#pragma unroll
    for (int i = 0; i < 8; ++i) acc[i] = make_float4(0.f, 0.f, 0.f, 0.f);
    for (int k = 0; k < 68; k += 4) {
        float4 a4[8], b4[4];
#pragma unroll
        for (int i = 0; i < 8; ++i) a4[i] = *(const float4*)&sin_[(rowg * 8 + i) * 68 + k];
#pragma unroll
        for (int kk = 0; kk < 4; ++kk) b4[kk] = *(const float4*)&sw[(k + kk) * 128 + colg * 4];
#pragma unroll
        for (int i = 0; i < 8; ++i) {
#pragma unroll
            for (int kk = 0; kk < 4; ++kk) {
                float av = (kk == 0) ? a4[i].x : (kk == 1) ? a4[i].y : (kk == 2) ? a4[i].z : a4[i].w;
                acc[i].x += av * b4[kk].x;
                acc[i].y += av * b4[kk].y;
                acc[i].z += av * b4[kk].z;
                acc[i].w += av * b4[kk].w;
            }
        }
    }
#pragma unroll
    for (int i = 0; i < 8; ++i) {
        f16x4 h;
        h[0] = (_Float16)acc[i].x; h[1] = (_Float16)acc[i].y;
        h[2] = (_Float16)acc[i].z; h[3] = (_Float16)acc[i].w;
        *(f16x4*)&Pp[(size_t)(row0 + rowg * 8 + i) * 128 + colg * 4] = h;
    }
}

// ---------------------------------------------------------------------------
// Kernel 2b: Q'[row,c] = b1[c] + f1.W1[64:128] - anchor.W1[128:131]; + anchors.
// Same tiling as k_pp; anchor xyz staged negated (exact) so one fma loop works.
// ---------------------------------------------------------------------------
__global__ __launch_bounds__(256) void k_qp(const float* __restrict__ xyzs,
                                            const float* __restrict__ feats,
                                            const float* __restrict__ w1,
                                            const float* __restrict__ b1,
                                            const int* __restrict__ fps_idx,
                                            float* __restrict__ Qp,
                                            float* __restrict__ out_anchor) {
    __shared__ float sw[68 * 128];
    __shared__ float sin_[64 * 68];
    __shared__ float sb[128];
    int tid = threadIdx.x;
    for (int i = tid; i < 68 * 128; i += 256) {
        int r = i >> 7, c = i & 127;
        float v = 0.f;
        if (r < 64) v = w1[(64 + r) * 128 + c];
        else if (r < 67) v = w1[(128 + r - 64) * 128 + c];
        sw[i] = v;
    }
    if (tid < 128) sb[tid] = b1[tid];
    int row0 = blockIdx.x * 64;
    int bt = row0 >> 9;
    size_t fbase = (size_t)bt * NN;
    {
        int r = tid >> 2, seg = tid & 3;
        int aidx = fps_idx[row0 + r];
        const float4* fr = (const float4*)(feats + (fbase + aidx) * CC);
#pragma unroll
        for (int i = 0; i < 4; ++i) {
            float4 v = fr[seg * 4 + i];
            *(float4*)&sin_[r * 68 + seg * 16 + i * 4] = v;
        }
    }
    if (tid < 64) {
        int aidx = fps_idx[row0 + tid];
        const float* xs = xyzs + (fbase + aidx) * 3;
        float x = xs[0], y = xs[1], z = xs[2];
        sin_[tid * 68 + 64] = -x;
        sin_[tid * 68 + 65] = -y;
        sin_[tid * 68 + 66] = -z;
        sin_[tid * 68 + 67] = 0.f;
        out_anchor[(size_t)(row0 + tid) * 3 + 0] = x;
        out_anchor[(size_t)(row0 + tid) * 3 + 1] = y;
        out_anchor[(size_t)(row0 + tid) * 3 + 2] = z;
    }
    __syncthreads();

    int rowg = tid >> 5, colg = tid & 31;
    float4 bias = *(const float4*)&sb[colg * 4];
    float4 acc[8];
#pragma unroll
    for (int i = 0; i < 8; ++i) acc[i] = bias;
    for (int k = 0; k < 68; k += 4) {
        float4 a4[8], b4[4];
#pragma unroll
        for (int i = 0; i < 8; ++i) a4[i] = *(const float4*)&sin_[(rowg * 8 + i) * 68 + k];
#pragma unroll
        for (int kk = 0; kk < 4; ++kk) b4[kk] = *(const float4*)&sw[(k + kk) * 128 + colg * 4];
#pragma unroll
        for (int i = 0; i < 8; ++i) {
#pragma unroll
            for (int kk = 0; kk < 4; ++kk) {
                float av = (kk == 0) ? a4[i].x : (kk == 1) ? a4[i].y : (kk == 2) ? a4[i].z : a4[i].w;
                acc[i].x += av * b4[kk].x;
                acc[i].y += av * b4[kk].y;
                acc[i].z += av * b4[kk].z;
                acc[i].w += av * b4[kk].w;
            }
        }
    }
#pragma unroll
    for (int i = 0; i < 8; ++i)
        *(float4*)&Qp[(size_t)(row0 + rowg * 8 + i) * 128 + colg * 4] = acc[i];
}

// ---------------------------------------------------------------------------
// Kernel 3: exact stable top-K=32 nearest + radius filter. One wave per anchor.
// ---------------------------------------------------------------------------
__global__ __launch_bounds__(256) void k_knn(const float* __restrict__ xyzs,
                                             const float* __restrict__ anchors,
                                             int* __restrict__ idxk) {
    __shared__ float sx[NN], sy[NN], sz[NN];
    int tid = threadIdx.x;
    int wave = tid >> 6, lane = tid & 63;
    int bt = blockIdx.x >> 5;
    int sub = blockIdx.x & 31;
    int b = bt >> 3, t = bt & 7;
    int tn = (t + 1 < TT) ? (t + 1) : (TT - 1);
    const float* src = xyzs + ((size_t)(b * TT + tn)) * NN * 3;
    for (int i = tid; i < NN; i += 256) {
        sx[i] = src[i * 3 + 0];
        sy[i] = src[i * 3 + 1];
        sz[i] = src[i * 3 + 2];
    }
    __syncthreads();

    for (int a = 0; a < 4; ++a) {
        int mrow = bt * MM + sub * 16 + wave * 4 + a;
        float ax = anchors[mrow * 3 + 0];
        float ay = anchors[mrow * 3 + 1];
        float az = anchors[mrow * 3 + 2];
        float d[32];
#pragma unroll
        for (int j = 0; j < 32; ++j) {
            int p = j * 64 + lane;
            float dx = sx[p] - ax, dy = sy[p] - ay, dz = sz[p] - az;
            d[j] = dx * dx + dy * dy + dz * dz;
        }
        int pstar = -1;
        int p0 = 0;
        for (int r = 0; r < KK; ++r) {
            float bestd = FINF;
            int bestp = 0x7fffffff;
#pragma unroll
            for (int j = 0; j < 32; ++j) {
                int pj = j * 64 + lane;
                float dj = (pj == pstar) ? FINF : d[j];
                d[j] = dj;
                if (dj < bestd) { bestd = dj; bestp = pj; }
            }
#pragma unroll
            for (int off = 32; off >= 1; off >>= 1) {
                float od = __shfl_xor(bestd, off);
                int   op = __shfl_xor(bestp, off);
                if (od < bestd || (od == bestd && op < bestp)) { bestd = od; bestp = op; }
            }
            if (r == 0) p0 = bestp;
            int outp = (bestd <= RAD2) ? bestp : p0;
            if (lane == 0) idxk[(size_t)mrow * KK + r] = outp;
            pstar = bestp;
        }
    }
}

// ---------------------------------------------------------------------------
// Kernel 4: persistent-block fp16 MFMA MLP (layers 2+3) + max over K.
// ---------------------------------------------------------------------------
#define SM_W2 0
#define SM_W3 32768
#define SM_H1 98304
#define SM_H2 114688
#define SM_B2 131072
#define SM_B3 131584
#define SM_TOTAL 132608

__global__ __launch_bounds__(256, 1) void k_mlp(const _Float16* __restrict__ Pp,
                                                const float* __restrict__ Qp,
                                                const int* __restrict__ idxk,
                                                const float* __restrict__ w2,
                                                const float* __restrict__ b2,
                                                const float* __restrict__ w3,
                                                const float* __restrict__ b3,
                                                float* __restrict__ out_feat) {
    extern __shared__ char smem[];
    int tid = threadIdx.x;
    int bid = blockIdx.x;                  // 0..255

    // ---- one-time weight staging (transposed to [n][k] fp16, swizzled) ----
    for (int i = tid; i < 128 * 128; i += 256) {
        int n = i & 127, kk = i >> 7;
        _Float16 v = (_Float16)w2[kk * 128 + n];
        *(_Float16*)(smem + SM_W2 + n * 256 + ((2 * kk) ^ ((n & 7) << 4))) = v;
    }
    for (int i = tid; i < 256 * 128; i += 256) {
        int n = i & 255, kk = i >> 8;
        _Float16 v = (_Float16)w3[kk * 256 + n];
        *(_Float16*)(smem + SM_W3 + n * 256 + ((2 * kk) ^ ((n & 7) << 4))) = v;
    }
    if (tid < 128) *(float*)(smem + SM_B2 + tid * 4) = b2[tid];
    *(float*)(smem + SM_B3 + tid * 4) = b3[tid];   // tid<256 always
    __syncthreads();

    int lane = tid & 63;
    int w = tid >> 6;
    int wm = w >> 1, wn = w & 1;           // wave grid: 2 anchors x 2 col-halves
    int l15 = lane & 15, g = lane >> 4;
    int hswz = (l15 & 7) << 4;             // swizzle for A-frag rows (row&7 == l15&7)

    const f32x4 zero4 = {0.f, 0.f, 0.f, 0.f};

    for (int c = 0; c < 32; ++c) {
        int a0 = bid * 64 + c * 2;         // global anchor row (anchor 0 of pair)
        int bt = a0 >> 9;

        // ---- build h1 = relu(P'[nk] + Q'[a]) -> fp16, swizzled [64][128] ----
        {
            int r = tid >> 2, seg = tid & 3;
            int arow = a0 + (r >> 5);
            int kidx = r & 31;
            int nk = idxk[(size_t)arow * KK + kidx];
            const _Float16* ps = Pp + ((size_t)(bt * NN + nk)) * 128 + seg * 32;
            const float* qs = Qp + (size_t)arow * 128 + seg * 32;
            int rowbase = SM_H1 + r * 256;
            int swz = (r & 7) << 4;
#pragma unroll
            for (int i = 0; i < 4; ++i) {
                f16x8 pv = *(const f16x8*)(ps + i * 8);
                f32x4 q0 = *(const f32x4*)(qs + i * 8);
                f32x4 q1 = *(const f32x4*)(qs + i * 8 + 4);
                f16x8 hv;
#pragma unroll
                for (int j = 0; j < 4; ++j) hv[j] = (_Float16)fmaxf((float)pv[j] + q0[j], 0.f);
#pragma unroll
                for (int j = 0; j < 4; ++j) hv[4 + j] = (_Float16)fmaxf((float)pv[4 + j] + q1[j], 0.f);
                *(f16x8*)(smem + rowbase + ((seg * 64 + i * 16) ^ swz)) = hv;
            }
        }
        __syncthreads();

        // ---- layer 2: h2 = relu(h1 @ w2 + b2) ----
        f32x4 acc2[2][4];
#pragma unroll
        for (int m = 0; m < 2; ++m)
#pragma unroll
            for (int n = 0; n < 4; ++n) acc2[m][n] = zero4;

#pragma unroll
        for (int ks = 0; ks < 4; ++ks) {
            int kbyte = ks * 64 + g * 16;
            f16x8 af[2], bf[4];
#pragma unroll
            for (int m = 0; m < 2; ++m) {
                int row = wm * 32 + m * 16 + l15;
                af[m] = *(const f16x8*)(smem + SM_H1 + row * 256 + (kbyte ^ hswz));
            }
#pragma unroll
            for (int n = 0; n < 4; ++n) {
                int col = wn * 64 + n * 16 + l15;
                bf[n] = *(const f16x8*)(smem + SM_W2 + col * 256 + (kbyte ^ hswz));
            }
#pragma unroll
            for (int m = 0; m < 2; ++m)
#pragma unroll
                for (int n = 0; n < 4; ++n)
                    acc2[m][n] = __builtin_amdgcn_mfma_f32_16x16x32_f16(af[m], bf[n], acc2[m][n], 0, 0, 0);
        }
        // epilogue: +b2, relu, fp16 -> h2 (swizzled scatter, 2B stores)
#pragma unroll
        for (int m = 0; m < 2; ++m)
#pragma unroll
            for (int n = 0; n < 4; ++n) {
                int col = wn * 64 + n * 16 + l15;
                float bb = *(const float*)(smem + SM_B2 + col * 4);
#pragma unroll
                for (int r = 0; r < 4; ++r) {
                    int row = wm * 32 + m * 16 + g * 4 + r;
                    float v = fmaxf(acc2[m][n][r] + bb, 0.f);
                    *(_Float16*)(smem + SM_H2 + row * 256 + ((2 * col) ^ ((row & 7) << 4))) = (_Float16)v;
                }
            }
        __syncthreads();

        // ---- layer 3: max_k(h2 @ w3), +b3, relu, store ----
        f32x4 acc3[2][8];
#pragma unroll
        for (int m = 0; m < 2; ++m)
#pragma unroll
            for (int n = 0; n < 8; ++n) acc3[m][n] = zero4;

#pragma unroll
        for (int ks = 0; ks < 4; ++ks) {
            int kbyte = ks * 64 + g * 16;
            f16x8 af[2], bf[8];
#pragma unroll
            for (int m = 0; m < 2; ++m) {
                int row = wm * 32 + m * 16 + l15;
                af[m] = *(const f16x8*)(smem + SM_H2 + row * 256 + (kbyte ^ hswz));
            }
#pragma unroll
            for (int n = 0; n < 8; ++n) {
                int col = wn * 128 + n * 16 + l15;
                bf[n] = *(const f16x8*)(smem + SM_W3 + col * 256 + (kbyte ^ hswz));
            }
#pragma unroll
            for (int m = 0; m < 2; ++m)
#pragma unroll
                for (int n = 0; n < 8; ++n)
                    acc3[m][n] = __builtin_amdgcn_mfma_f32_16x16x32_f16(af[m], bf[n], acc3[m][n], 0, 0, 0);
        }
#pragma unroll
        for (int n = 0; n < 8; ++n) {
            int col = wn * 128 + n * 16 + l15;
            float s = acc3[0][n][0];
#pragma unroll
            for (int r = 1; r < 4; ++r) s = fmaxf(s, acc3[0][n][r]);
#pragma unroll
            for (int r = 0; r < 4; ++r) s = fmaxf(s, acc3[1][n][r]);
            s = fmaxf(s, __shfl_xor(s, 16));
            s = fmaxf(s, __shfl_xor(s, 32));
            if (g == 0) {
                float bb = *(const float*)(smem + SM_B3 + col * 4);
                out_feat[(size_t)(a0 + wm) * H3DIM + col] = fmaxf(s + bb, 0.f);
            }
        }
        __syncthreads();   // h2 (and h1) free for next chunk
    }
}

// ---------------------------------------------------------------------------
extern "C" void kernel_launch(void* const* d_in, const int* in_sizes, int n_in,
                              void* d_out, int out_size, void* d_ws, size_t ws_size,
                              hipStream_t stream) {
    const float* xyzs  = (const float*)d_in[0];
    const float* feats = (const float*)d_in[1];
    const float* w1 = (const float*)d_in[2];
    const float* b1 = (const float*)d_in[3];
    const float* w2 = (const float*)d_in[4];
    const float* b2 = (const float*)d_in[5];
    const float* w3 = (const float*)d_in[6];
    const float* b3 = (const float*)d_in[7];

    float* out_anchor = (float*)d_out;
    float* out_feat = out_anchor + (size_t)BB * TT * MM * 3;

    // workspace layout
    char* ws = (char*)d_ws;
    int* fps_idx = (int*)ws;                                   // 64 KB
    int* idxk = (int*)(ws + 65536);                            // 2 MB
    _Float16* Pp = (_Float16*)(ws + 65536 + 2097152);          // B*T*N*128 fp16 = 16 MB
    float* Qp = (float*)(ws + 65536 + 2097152 + 16777216);     // B*T*M*128 fp32 = 8 MB
    if (ws_size < (size_t)(65536 + 2097152 + 16777216) + (size_t)BB * TT * MM * 128 * 4)
        return;

    k_fps<<<BB * TT, 256, 0, stream>>>(xyzs, fps_idx);
    k_pp<<<BB * TT * NN / 64, 256, 0, stream>>>(xyzs, feats, w1, Pp);
    k_qp<<<BB * TT * MM / 64, 256, 0, stream>>>(xyzs, feats, w1, b1, fps_idx, Qp, out_anchor);
    k_knn<<<BB * TT * 32, 256, 0, stream>>>(xyzs, out_anchor, idxk);

    (void)hipFuncSetAttribute((const void*)k_mlp, hipFuncAttributeMaxDynamicSharedMemorySize, SM_TOTAL);
    k_mlp<<<256, 256, SM_TOTAL, stream>>>(Pp, Qp, idxk, w2, b2, w3, b3, out_feat);
}

// Round 5
// 595.773 us; speedup vs baseline: 3.1816x; 1.2061x over previous
//
#include <hip/hip_runtime.h>

// Problem constants (B=4, T=8, N=2048, C=64)
#define BB 4
#define TT 8
#define NN 2048
#define CC 64
#define MM 512           // N / SPATIAL_STRIDE
#define KK 32
#define H3DIM 256
#define RAD2 0.25f
#define FINF 3.4e38f

typedef _Float16 f16x8 __attribute__((ext_vector_type(8)));
typedef _Float16 f16x4 __attribute__((ext_vector_type(4)));
typedef float f32x4 __attribute__((ext_vector_type(4)));

// ---------------------------------------------------------------------------
// DPP wave-64 reduce trees (row_shr 1/2/4/8 + row_bcast15/31, result in lane63).
// Pattern HW-validated by k_fps in rounds 2/4.
// ---------------------------------------------------------------------------
template <int CTRL>
__device__ __forceinline__ float dpp_max_step(float x) {
    int xi = __builtin_bit_cast(int, x);
    int yi = __builtin_amdgcn_update_dpp(xi, xi, CTRL, 0xf, 0xf, false);
    return fmaxf(x, __builtin_bit_cast(float, yi));
}
__device__ __forceinline__ float wave_max64(float x) {
    x = dpp_max_step<0x111>(x);
    x = dpp_max_step<0x112>(x);
    x = dpp_max_step<0x114>(x);
    x = dpp_max_step<0x118>(x);
    x = dpp_max_step<0x142>(x);
    x = dpp_max_step<0x143>(x);
    return __builtin_bit_cast(float, __builtin_amdgcn_readlane(__builtin_bit_cast(int, x), 63));
}
template <int CTRL>
__device__ __forceinline__ float dpp_min_step(float x) {
    int xi = __builtin_bit_cast(int, x);
    int yi = __builtin_amdgcn_update_dpp(xi, xi, CTRL, 0xf, 0xf, false);
    return fminf(x, __builtin_bit_cast(float, yi));
}
__device__ __forceinline__ float wave_minf64(float x) {
    x = dpp_min_step<0x111>(x);
    x = dpp_min_step<0x112>(x);
    x = dpp_min_step<0x114>(x);
    x = dpp_min_step<0x118>(x);
    x = dpp_min_step<0x142>(x);
    x = dpp_min_step<0x143>(x);
    return __builtin_bit_cast(float, __builtin_amdgcn_readlane(__builtin_bit_cast(int, x), 63));
}
template <int CTRL>
__device__ __forceinline__ int dpp_imin_step(int x) {
    int yi = __builtin_amdgcn_update_dpp(x, x, CTRL, 0xf, 0xf, false);
    return (yi < x) ? yi : x;
}
__device__ __forceinline__ int wave_mini64(int x) {
    x = dpp_imin_step<0x111>(x);
    x = dpp_imin_step<0x112>(x);
    x = dpp_imin_step<0x114>(x);
    x = dpp_imin_step<0x118>(x);
    x = dpp_imin_step<0x142>(x);
    x = dpp_imin_step<0x143>(x);
    return __builtin_amdgcn_readlane(x, 63);
}

// ---------------------------------------------------------------------------
// Kernel 1: farthest point sampling. 4 waves (256 thr) per (b,t) cloud.
// (unchanged from round 4 — verified)
// ---------------------------------------------------------------------------
__global__ __launch_bounds__(256) void k_fps(const float* __restrict__ xyzs,
                                             int* __restrict__ fps_idx) {
    int bt = blockIdx.x;
    int tid = threadIdx.x;
    int lane = tid & 63, w = tid >> 6;
    __shared__ float sx[NN], sy[NN], sz[NN];
    __shared__ float pd[2][4];
    __shared__ int   pi[2][4];
    const float* src = xyzs + (size_t)bt * NN * 3;
    for (int i = tid; i < NN; i += 256) {
        sx[i] = src[i * 3 + 0];
        sy[i] = src[i * 3 + 1];
        sz[i] = src[i * 3 + 2];
    }
    __syncthreads();

    float px[8], py[8], pz[8], dist[8];
#pragma unroll
    for (int j = 0; j < 8; ++j) {
        int p = tid * 8 + j;
        px[j] = sx[p]; py[j] = sy[p]; pz[j] = sz[p];
        dist[j] = 1e10f;
    }

    int cur = 0;
    if (tid == 0) fps_idx[bt * MM + 0] = 0;
    int pbase = tid * 8;

    for (int it = 1; it < MM; ++it) {
        float cx = sx[cur], cy = sy[cur], cz = sz[cur];
        float bestd = -1.0f;
        int bestp = 0;
#pragma unroll
        for (int j = 0; j < 8; ++j) {
            float dx = px[j] - cx, dy = py[j] - cy, dz = pz[j] - cz;
            float d = dx * dx + dy * dy + dz * dz;
            float nd = fminf(dist[j], d);
            dist[j] = nd;
            if (nd > bestd) { bestd = nd; bestp = pbase + j; }
        }
        float wmax = wave_max64(bestd);
        unsigned long long mask = __ballot(bestd == wmax);
        int wl = __ffsll(mask) - 1;
        int wbp = __builtin_amdgcn_readlane(bestp, wl);
        if (lane == 0) { pd[it & 1][w] = wmax; pi[it & 1][w] = wbp; }
        __syncthreads();
        float bd = pd[it & 1][0];
        int bp = pi[it & 1][0];
#pragma unroll
        for (int q = 1; q < 4; ++q) {
            float d2 = pd[it & 1][q];
            int p2 = pi[it & 1][q];
            if (d2 > bd) { bd = d2; bp = p2; }
        }
        cur = bp;
        if (tid == 0) fps_idx[bt * MM + it] = cur;
    }
}

// ---------------------------------------------------------------------------
// Kernel 2a: P'[row,c] (fp16) = feat_n.W1[0:64] + xyz_n.W1[128:131]
// (unchanged from round 4 — verified)
// ---------------------------------------------------------------------------
__global__ __launch_bounds__(256) void k_pp(const float* __restrict__ xyzs,
                                            const float* __restrict__ feats,
                                            const float* __restrict__ w1,
                                            _Float16* __restrict__ Pp) {
    __shared__ float sw[68 * 128];
    __shared__ float sin_[64 * 68];
    int tid = threadIdx.x;
    for (int i = tid; i < 68 * 128; i += 256) {
        int r = i >> 7, c = i & 127;
        float v = 0.f;
        if (r < 64) v = w1[r * 128 + c];
        else if (r < 67) v = w1[(128 + r - 64) * 128 + c];
        sw[i] = v;
    }
    int row0 = blockIdx.x * 64;
    int bt = row0 >> 11;
    int b = bt >> 3, t = bt & 7;
    int tn = (t + 1 < TT) ? (t + 1) : (TT - 1);
    size_t nbase = (size_t)(b * TT + tn) * NN + (row0 & (NN - 1));
    const float* fsrc = feats + nbase * CC;
    const float* xsrc = xyzs + nbase * 3;
    for (int i = tid; i < 1024; i += 256) {
        float4 v = ((const float4*)fsrc)[i];
        int r = i >> 4, c = (i & 15) * 4;
        *(float4*)&sin_[r * 68 + c] = v;
    }
    if (tid < 192) {
        int r = tid / 3, c = tid - r * 3;
        sin_[r * 68 + 64 + c] = xsrc[tid];
    }
    if (tid < 64) sin_[tid * 68 + 67] = 0.f;
    __syncthreads();

    int rowg = tid >> 5, colg = tid & 31;
    float4 acc[8];
#pragma unroll
    for (int i = 0; i < 8; ++i) acc[i] = make_float4(0.f, 0.f, 0.f, 0.f);
    for (int k = 0; k < 68; k += 4) {
        float4 a4[8], b4[4];
#pragma unroll
        for (int i = 0; i < 8; ++i) a4[i] = *(const float4*)&sin_[(rowg * 8 + i) * 68 + k];
#pragma unroll
        for (int kk = 0; kk < 4; ++kk) b4[kk] = *(const float4*)&sw[(k + kk) * 128 + colg * 4];
#pragma unroll
        for (int i = 0; i < 8; ++i) {
#pragma unroll
            for (int kk = 0; kk < 4; ++kk) {
                float av = (kk == 0) ? a4[i].x : (kk == 1) ? a4[i].y : (kk == 2) ? a4[i].z : a4[i].w;
                acc[i].x += av * b4[kk].x;
                acc[i].y += av * b4[kk].y;
                acc[i].z += av * b4[kk].z;
                acc[i].w += av * b4[kk].w;
            }
        }
    }
#pragma unroll
    for (int i = 0; i < 8; ++i) {
        f16x4 h;
        h[0] = (_Float16)acc[i].x; h[1] = (_Float16)acc[i].y;
        h[2] = (_Float16)acc[i].z; h[3] = (_Float16)acc[i].w;
        *(f16x4*)&Pp[(size_t)(row0 + rowg * 8 + i) * 128 + colg * 4] = h;
    }
}

// ---------------------------------------------------------------------------
// Kernel 2b: Q' + anchors. (unchanged from round 4 — verified)
// ---------------------------------------------------------------------------
__global__ __launch_bounds__(256) void k_qp(const float* __restrict__ xyzs,
                                            const float* __restrict__ feats,
                                            const float* __restrict__ w1,
                                            const float* __restrict__ b1,
                                            const int* __restrict__ fps_idx,
                                            float* __restrict__ Qp,
                                            float* __restrict__ out_anchor) {
    __shared__ float sw[68 * 128];
    __shared__ float sin_[64 * 68];
    __shared__ float sb[128];
    int tid = threadIdx.x;
    for (int i = tid; i < 68 * 128; i += 256) {
        int r = i >> 7, c = i & 127;
        float v = 0.f;
        if (r < 64) v = w1[(64 + r) * 128 + c];
        else if (r < 67) v = w1[(128 + r - 64) * 128 + c];
        sw[i] = v;
    }
    if (tid < 128) sb[tid] = b1[tid];
    int row0 = blockIdx.x * 64;
    int bt = row0 >> 9;
    size_t fbase = (size_t)bt * NN;
    {
        int r = tid >> 2, seg = tid & 3;
        int aidx = fps_idx[row0 + r];
        const float4* fr = (const float4*)(feats + (fbase + aidx) * CC);
#pragma unroll
        for (int i = 0; i < 4; ++i) {
            float4 v = fr[seg * 4 + i];
            *(float4*)&sin_[r * 68 + seg * 16 + i * 4] = v;
        }
    }
    if (tid < 64) {
        int aidx = fps_idx[row0 + tid];
        const float* xs = xyzs + (fbase + aidx) * 3;
        float x = xs[0], y = xs[1], z = xs[2];
        sin_[tid * 68 + 64] = -x;
        sin_[tid * 68 + 65] = -y;
        sin_[tid * 68 + 66] = -z;
        sin_[tid * 68 + 67] = 0.f;
        out_anchor[(size_t)(row0 + tid) * 3 + 0] = x;
        out_anchor[(size_t)(row0 + tid) * 3 + 1] = y;
        out_anchor[(size_t)(row0 + tid) * 3 + 2] = z;
    }
    __syncthreads();

    int rowg = tid >> 5, colg = tid & 31;
    float4 bias = *(const float4*)&sb[colg * 4];
    float4 acc[8];
#pragma unroll
    for (int i = 0; i < 8; ++i) acc[i] = bias;
    for (int k = 0; k < 68; k += 4) {
        float4 a4[8], b4[4];
#pragma unroll
        for (int i = 0; i < 8; ++i) a4[i] = *(const float4*)&sin_[(rowg * 8 + i) * 68 + k];
#pragma unroll
        for (int kk = 0; kk < 4; ++kk) b4[kk] = *(const float4*)&sw[(k + kk) * 128 + colg * 4];
#pragma unroll
        for (int i = 0; i < 8; ++i) {
#pragma unroll
            for (int kk = 0; kk < 4; ++kk) {
                float av = (kk == 0) ? a4[i].x : (kk == 1) ? a4[i].y : (kk == 2) ? a4[i].z : a4[i].w;
                acc[i].x += av * b4[kk].x;
                acc[i].y += av * b4[kk].y;
                acc[i].z += av * b4[kk].z;
                acc[i].w += av * b4[kk].w;
            }
        }
    }
#pragma unroll
    for (int i = 0; i < 8; ++i)
        *(float4*)&Qp[(size_t)(row0 + rowg * 8 + i) * 128 + colg * 4] = acc[i];
}

// ---------------------------------------------------------------------------
// Kernel 3: exact stable top-K=32 nearest + radius filter.
// One wave per anchor, 2 serial anchors/wave, 2048 blocks (75% occ potential).
// DPP min-reduce (value) + DPP i32 min-reduce (index tie-break) — no shfl.
// Distance math, tie-break, and radius semantics bit-identical to round 4.
// ---------------------------------------------------------------------------
__global__ __launch_bounds__(256) void k_knn(const float* __restrict__ xyzs,
                                             const float* __restrict__ anchors,
                                             int* __restrict__ idxk) {
    __shared__ float sx[NN], sy[NN], sz[NN];
    int tid = threadIdx.x;
    int wave = tid >> 6, lane = tid & 63;
    int bt = blockIdx.x >> 6;              // 64 blocks per (b,t)
    int sub = blockIdx.x & 63;
    int b = bt >> 3, t = bt & 7;
    int tn = (t + 1 < TT) ? (t + 1) : (TT - 1);
    const float* src = xyzs + ((size_t)(b * TT + tn)) * NN * 3;
    for (int i = tid; i < NN; i += 256) {
        sx[i] = src[i * 3 + 0];
        sy[i] = src[i * 3 + 1];
        sz[i] = src[i * 3 + 2];
    }
    __syncthreads();

    for (int a = 0; a < 2; ++a) {
        int mrow = bt * MM + sub * 8 + wave * 2 + a;
        float ax = anchors[mrow * 3 + 0];
        float ay = anchors[mrow * 3 + 1];
        float az = anchors[mrow * 3 + 2];
        float d[32];
#pragma unroll
        for (int j = 0; j < 32; ++j) {
            int p = j * 64 + lane;
            float dx = sx[p] - ax, dy = sy[p] - ay, dz = sz[p] - az;
            d[j] = dx * dx + dy * dy + dz * dz;
        }
        // round 0 (no invalidation)
        float bd = FINF;
        int bp = 0x7fffffff;
#pragma unroll
        for (int j = 0; j < 32; ++j) {
            if (d[j] < bd) { bd = d[j]; bp = j * 64 + lane; }  // strict < : smallest p in lane
        }
        float wmin = wave_minf64(bd);
        int cand = (bd == wmin) ? bp : 0x7fffffff;
        int gp = wave_mini64(cand);        // smallest p among global-min ties
        int p0 = gp;
        int myidx = gp;                    // lane 0's output (r=0); others overwritten below
        int pstar = gp;

        for (int r = 1; r < KK; ++r) {
            bd = FINF;
            bp = 0x7fffffff;
#pragma unroll
            for (int j = 0; j < 32; ++j) {
                int pj = j * 64 + lane;
                float dj = (pj == pstar) ? FINF : d[j];   // invalidate last winner
                d[j] = dj;
                if (dj < bd) { bd = dj; bp = pj; }
            }
            wmin = wave_minf64(bd);
            cand = (bd == wmin) ? bp : 0x7fffffff;
            gp = wave_mini64(cand);
            int outp = (wmin <= RAD2) ? gp : p0;          // radius replacement
            if (lane == r) myidx = outp;
            pstar = gp;
        }
        if (lane < KK) idxk[(size_t)mrow * KK + lane] = myidx;
    }
}

// ---------------------------------------------------------------------------
// Kernel 4: persistent-block fp16 MFMA MLP (layers 2+3) + max over K.
// Now 512 threads / 8 waves (2 waves/SIMD) — wave grid 2 anchors x 4 col-groups.
// Same LDS layout, fragment layout, and per-output MFMA order as round 4
// (bitwise-identical results; only wave tiling changed).
// ---------------------------------------------------------------------------
#define SM_W2 0
#define SM_W3 32768
#define SM_H1 98304
#define SM_H2 114688
#define SM_B2 131072
#define SM_B3 131584
#define SM_TOTAL 132608

__global__ __launch_bounds__(512, 1) void k_mlp(const _Float16* __restrict__ Pp,
                                                const float* __restrict__ Qp,
                                                const int* __restrict__ idxk,
                                                const float* __restrict__ w2,
                                                const float* __restrict__ b2,
                                                const float* __restrict__ w3,
                                                const float* __restrict__ b3,
                                                float* __restrict__ out_feat) {
    extern __shared__ char smem[];
    int tid = threadIdx.x;
    int bid = blockIdx.x;                  // 0..255

    // ---- one-time weight staging (transposed to [n][k] fp16, swizzled) ----
    for (int i = tid; i < 128 * 128; i += 512) {
        int n = i & 127, kk = i >> 7;
        _Float16 v = (_Float16)w2[kk * 128 + n];
        *(_Float16*)(smem + SM_W2 + n * 256 + ((2 * kk) ^ ((n & 7) << 4))) = v;
    }
    for (int i = tid; i < 256 * 128; i += 512) {
        int n = i & 255, kk = i >> 8;
        _Float16 v = (_Float16)w3[kk * 256 + n];
        *(_Float16*)(smem + SM_W3 + n * 256 + ((2 * kk) ^ ((n & 7) << 4))) = v;
    }
    if (tid < 128) *(float*)(smem + SM_B2 + tid * 4) = b2[tid];
    if (tid < 256) *(float*)(smem + SM_B3 + tid * 4) = b3[tid];
    __syncthreads();

    int lane = tid & 63;
    int w = tid >> 6;                      // 0..7
    int wm = w >> 2, wn = w & 3;           // 2 anchors x 4 col-groups
    int l15 = lane & 15, g = lane >> 4;
    int hswz = (l15 & 7) << 4;

    const f32x4 zero4 = {0.f, 0.f, 0.f, 0.f};

    for (int c = 0; c < 32; ++c) {
        int a0 = bid * 64 + c * 2;
        int bt = a0 >> 9;

        // ---- build h1 = relu(P'[nk] + Q'[a]) -> fp16, swizzled [64][128] ----
        {
            int r = tid >> 3, seg = tid & 7;       // 64 rows x 8 col-segments(16)
            int arow = a0 + (r >> 5);
            int kidx = r & 31;
            int nk = idxk[(size_t)arow * KK + kidx];
            const _Float16* ps = Pp + ((size_t)(bt * NN + nk)) * 128 + seg * 16;
            const float* qs = Qp + (size_t)arow * 128 + seg * 16;
            int rowbase = SM_H1 + r * 256;
            int swz = (r & 7) << 4;
#pragma unroll
            for (int i = 0; i < 2; ++i) {
                f16x8 pv = *(const f16x8*)(ps + i * 8);
                f32x4 q0 = *(const f32x4*)(qs + i * 8);
                f32x4 q1 = *(const f32x4*)(qs + i * 8 + 4);
                f16x8 hv;
#pragma unroll
                for (int j = 0; j < 4; ++j) hv[j] = (_Float16)fmaxf((float)pv[j] + q0[j], 0.f);
#pragma unroll
                for (int j = 0; j < 4; ++j) hv[4 + j] = (_Float16)fmaxf((float)pv[4 + j] + q1[j], 0.f);
                *(f16x8*)(smem + rowbase + ((seg * 32 + i * 16) ^ swz)) = hv;
            }
        }
        __syncthreads();

        // ---- layer 2: h2 = relu(h1 @ w2 + b2); wave tile 32 rows x 32 cols ----
        f32x4 acc2[2][2];
#pragma unroll
        for (int m = 0; m < 2; ++m)
#pragma unroll
            for (int n = 0; n < 2; ++n) acc2[m][n] = zero4;

#pragma unroll
        for (int ks = 0; ks < 4; ++ks) {
            int kbyte = ks * 64 + g * 16;
            f16x8 af[2], bf[2];
#pragma unroll
            for (int m = 0; m < 2; ++m) {
                int row = wm * 32 + m * 16 + l15;
                af[m] = *(const f16x8*)(smem + SM_H1 + row * 256 + (kbyte ^ hswz));
            }
#pragma unroll
            for (int n = 0; n < 2; ++n) {
                int col = wn * 32 + n * 16 + l15;
                bf[n] = *(const f16x8*)(smem + SM_W2 + col * 256 + (kbyte ^ hswz));
            }
#pragma unroll
            for (int m = 0; m < 2; ++m)
#pragma unroll
                for (int n = 0; n < 2; ++n)
                    acc2[m][n] = __builtin_amdgcn_mfma_f32_16x16x32_f16(af[m], bf[n], acc2[m][n], 0, 0, 0);
        }
#pragma unroll
        for (int m = 0; m < 2; ++m)
#pragma unroll
            for (int n = 0; n < 2; ++n) {
                int col = wn * 32 + n * 16 + l15;
                float bb = *(const float*)(smem + SM_B2 + col * 4);
#pragma unroll
                for (int r = 0; r < 4; ++r) {
                    int row = wm * 32 + m * 16 + g * 4 + r;
                    float v = fmaxf(acc2[m][n][r] + bb, 0.f);
                    *(_Float16*)(smem + SM_H2 + row * 256 + ((2 * col) ^ ((row & 7) << 4))) = (_Float16)v;
                }
            }
        __syncthreads();

        // ---- layer 3: max_k(h2 @ w3); wave tile 32 rows x 64 cols ----
        f32x4 acc3[2][4];
#pragma unroll
        for (int m = 0; m < 2; ++m)
#pragma unroll
            for (int n = 0; n < 4; ++n) acc3[m][n] = zero4;

#pragma unroll
        for (int ks = 0; ks < 4; ++ks) {
            int kbyte = ks * 64 + g * 16;
            f16x8 af[2], bf[4];
#pragma unroll
            for (int m = 0; m < 2; ++m) {
                int row = wm * 32 + m * 16 + l15;
                af[m] = *(const f16x8*)(smem + SM_H2 + row * 256 + (kbyte ^ hswz));
            }
#pragma unroll
            for (int n = 0; n < 4; ++n) {
                int col = wn * 64 + n * 16 + l15;
                bf[n] = *(const f16x8*)(smem + SM_W3 + col * 256 + (kbyte ^ hswz));
            }
#pragma unroll
            for (int m = 0; m < 2; ++m)
#pragma unroll
                for (int n = 0; n < 4; ++n)
                    acc3[m][n] = __builtin_amdgcn_mfma_f32_16x16x32_f16(af[m], bf[n], acc3[m][n], 0, 0, 0);
        }
#pragma unroll
        for (int n = 0; n < 4; ++n) {
            int col = wn * 64 + n * 16 + l15;
            float s = acc3[0][n][0];
#pragma unroll
            for (int r = 1; r < 4; ++r) s = fmaxf(s, acc3[0][n][r]);
#pragma unroll
            for (int r = 0; r < 4; ++r) s = fmaxf(s, acc3[1][n][r]);
            s = fmaxf(s, __shfl_xor(s, 16));
            s = fmaxf(s, __shfl_xor(s, 32));
            if (g == 0) {
                float bb = *(const float*)(smem + SM_B3 + col * 4);
                out_feat[(size_t)(a0 + wm) * H3DIM + col] = fmaxf(s + bb, 0.f);
            }
        }
        __syncthreads();
    }
}

// ---------------------------------------------------------------------------
extern "C" void kernel_launch(void* const* d_in, const int* in_sizes, int n_in,
                              void* d_out, int out_size, void* d_ws, size_t ws_size,
                              hipStream_t stream) {
    const float* xyzs  = (const float*)d_in[0];
    const float* feats = (const float*)d_in[1];
    const float* w1 = (const float*)d_in[2];
    const float* b1 = (const float*)d_in[3];
    const float* w2 = (const float*)d_in[4];
    const float* b2 = (const float*)d_in[5];
    const float* w3 = (const float*)d_in[6];
    const float* b3 = (const float*)d_in[7];

    float* out_anchor = (float*)d_out;
    float* out_feat = out_anchor + (size_t)BB * TT * MM * 3;

    // workspace layout
    char* ws = (char*)d_ws;
    int* fps_idx = (int*)ws;                                   // 64 KB
    int* idxk = (int*)(ws + 65536);                            // 2 MB
    _Float16* Pp = (_Float16*)(ws + 65536 + 2097152);          // B*T*N*128 fp16 = 16 MB
    float* Qp = (float*)(ws + 65536 + 2097152 + 16777216);     // B*T*M*128 fp32 = 8 MB
    if (ws_size < (size_t)(65536 + 2097152 + 16777216) + (size_t)BB * TT * MM * 128 * 4)
        return;

    k_fps<<<BB * TT, 256, 0, stream>>>(xyzs, fps_idx);
    k_pp<<<BB * TT * NN / 64, 256, 0, stream>>>(xyzs, feats, w1, Pp);
    k_qp<<<BB * TT * MM / 64, 256, 0, stream>>>(xyzs, feats, w1, b1, fps_idx, Qp, out_anchor);
    k_knn<<<BB * TT * 64, 256, 0, stream>>>(xyzs, out_anchor, idxk);

    (void)hipFuncSetAttribute((const void*)k_mlp, hipFuncAttributeMaxDynamicSharedMemorySize, SM_TOTAL);
    k_mlp<<<256, 512, SM_TOTAL, stream>>>(Pp, Qp, idxk, w2, b2, w3, b3, out_feat);
}